// Round 9
// baseline (566.706 us; speedup 1.0000x reference)
//
#include <hip/hip_runtime.h>
#include <hip/hip_bf16.h>
#include <math.h>

#define L_SEQ 2048
#define DMODEL 2048
#define PROJW 3072
#define NQH 32
#define NKVH 8
#define HD 64
#define SW 512

typedef __attribute__((ext_vector_type(8))) short bf16x8;
typedef __attribute__((ext_vector_type(4))) float f32x4;

__device__ __forceinline__ ushort f2bf(float x) {
    __hip_bfloat16 h = __float2bfloat16(x);
    return *reinterpret_cast<ushort*>(&h);
}
__device__ __forceinline__ float bf2f(ushort u) {
    __hip_bfloat16 h = *reinterpret_cast<__hip_bfloat16*>(&u);
    return __bfloat162float(h);
}

__device__ __forceinline__ void glds16(const void* g, void* l) {
    __builtin_amdgcn_global_load_lds(
        (__attribute__((address_space(1))) void*)(void*)g,
        (__attribute__((address_space(3))) void*)l, 16, 0, 0);
}

// ---------------- RoPE tables: cos/sin (L x 32) ----------------
__global__ void rope_tables_kernel(float* __restrict__ cosT, float* __restrict__ sinT) {
    int pos = blockIdx.x * blockDim.x + threadIdx.x;
    if (pos >= L_SEQ) return;
    #pragma unroll
    for (int j = 0; j < 32; ++j) {
        float c, s;
        if (j < 16) {
            float t = (float)j * (1.0f / 15.0f);
            float freq = powf(1.0f / 1024.0f, t);
            float th = (float)pos * freq;
            sincosf(th, &s, &c);
        } else {
            c = 1.0f; s = 0.0f;
        }
        cosT[pos * 32 + j] = c;
        sinT[pos * 32 + j] = s;
    }
}

// ---------------- fp32 -> bf16 hi/lo split, same layout ----------------
__global__ __launch_bounds__(256) void split_rm_kernel(const float* __restrict__ A,
                                                       ushort* __restrict__ hi,
                                                       ushort* __restrict__ lo) {
    int i = (blockIdx.x * 256 + threadIdx.x) * 4;
    float4 v = *reinterpret_cast<const float4*>(&A[i]);
    float vv[4] = {v.x, v.y, v.z, v.w};
    ushort h[4], l[4];
    #pragma unroll
    for (int j = 0; j < 4; ++j) {
        h[j] = f2bf(vv[j]);
        l[j] = f2bf(vv[j] - bf2f(h[j]));
    }
    *reinterpret_cast<ushort4*>(&hi[i]) = make_ushort4(h[0], h[1], h[2], h[3]);
    *reinterpret_cast<ushort4*>(&lo[i]) = make_ushort4(l[0], l[1], l[2], l[3]);
}

// ---------------- fp32 W(KxN) -> bf16 hi/lo transposed Wt(NxK) ----------------
__global__ __launch_bounds__(256) void split_t_kernel(const float* __restrict__ W,
                                                      ushort* __restrict__ hi,
                                                      ushort* __restrict__ lo,
                                                      int K, int N) {
    __shared__ float t[32][33];
    int n0 = blockIdx.x * 32, k0 = blockIdx.y * 32;
    int tx = threadIdx.x & 31, ty = threadIdx.x >> 5;   // ty 0..7
    #pragma unroll
    for (int r = 0; r < 32; r += 8)
        t[ty + r][tx] = W[(size_t)(k0 + ty + r) * N + n0 + tx];
    __syncthreads();
    #pragma unroll
    for (int r = 0; r < 32; r += 8) {
        float v = t[tx][ty + r];                        // = W[k0+tx][n0+ty+r]
        ushort h = f2bf(v);
        ushort l = f2bf(v - bf2f(h));
        size_t o = (size_t)(n0 + ty + r) * K + k0 + tx; // Wt[n][k]
        hi[o] = h;
        lo[o] = l;
    }
}

// ---------------- bf16x2 MFMA GEMM (unchanged, validated round 2) --------
#define GBK 32

__global__ __launch_bounds__(256) void gemm_bf16x2_kernel(
    const ushort* __restrict__ Ahi, const ushort* __restrict__ Alo,
    const ushort* __restrict__ Bhi, const ushort* __restrict__ Blo,
    float* __restrict__ C, int M, int N, int K)
{
    __shared__ __align__(16) ushort sAh[128 * 32];
    __shared__ __align__(16) ushort sAl[128 * 32];
    __shared__ __align__(16) ushort sBh[128 * 32];
    __shared__ __align__(16) ushort sBl[128 * 32];

    const int tid = threadIdx.x;
    const int w = tid >> 6, lane = tid & 63;
    const int bm = blockIdx.y * 128, bn = blockIdx.x * 128;
    const int wr = w >> 1, wc = w & 1;

    f32x4 acc[4][4];
    #pragma unroll
    for (int i = 0; i < 4; ++i)
        #pragma unroll
        for (int j = 0; j < 4; ++j)
            acc[i][j] = (f32x4){0.0f, 0.0f, 0.0f, 0.0f};

    const int q0 = w * 128 + lane;
    const int q1 = q0 + 64;
    const int r0 = q0 >> 2, r1 = q1 >> 2;
    const int ks0 = ((q0 & 3) ^ (r0 & 3)) * 8;
    const int ks1 = ((q1 & 3) ^ (r1 & 3)) * 8;
    const ushort* gAh0 = Ahi + (size_t)(bm + r0) * K + ks0;
    const ushort* gAh1 = Ahi + (size_t)(bm + r1) * K + ks1;
    const ushort* gAl0 = Alo + (size_t)(bm + r0) * K + ks0;
    const ushort* gAl1 = Alo + (size_t)(bm + r1) * K + ks1;
    const ushort* gBh0 = Bhi + (size_t)(bn + r0) * K + ks0;
    const ushort* gBh1 = Bhi + (size_t)(bn + r1) * K + ks1;
    const ushort* gBl0 = Blo + (size_t)(bn + r0) * K + ks0;
    const ushort* gBl1 = Blo + (size_t)(bn + r1) * K + ks1;
    ushort* dAh0 = sAh + (w * 2 + 0) * 512;
    ushort* dAh1 = sAh + (w * 2 + 1) * 512;
    ushort* dAl0 = sAl + (w * 2 + 0) * 512;
    ushort* dAl1 = sAl + (w * 2 + 1) * 512;
    ushort* dBh0 = sBh + (w * 2 + 0) * 512;
    ushort* dBh1 = sBh + (w * 2 + 1) * 512;
    ushort* dBl0 = sBl + (w * 2 + 0) * 512;
    ushort* dBl1 = sBl + (w * 2 + 1) * 512;

    const int kg = lane >> 4;
    const int fr = lane & 15;

    for (int k0 = 0; k0 < K; k0 += GBK) {
        __syncthreads();
        glds16(gAh0 + k0, dAh0);
        glds16(gAh1 + k0, dAh1);
        glds16(gBh0 + k0, dBh0);
        glds16(gBh1 + k0, dBh1);
        glds16(gAl0 + k0, dAl0);
        glds16(gAl1 + k0, dAl1);
        glds16(gBl0 + k0, dBl0);
        glds16(gBl1 + k0, dBl1);
        __syncthreads();

        bf16x8 ah[4], al[4], bh[4], bl[4];
        #pragma unroll
        for (int i = 0; i < 4; ++i) {
            int row = wr * 64 + i * 16 + fr;
            int off = row * 32 + ((kg ^ (row & 3)) * 8);
            ah[i] = *reinterpret_cast<const bf16x8*>(&sAh[off]);
            al[i] = *reinterpret_cast<const bf16x8*>(&sAl[off]);
        }
        #pragma unroll
        for (int j = 0; j < 4; ++j) {
            int row = wc * 64 + j * 16 + fr;
            int off = row * 32 + ((kg ^ (row & 3)) * 8);
            bh[j] = *reinterpret_cast<const bf16x8*>(&sBh[off]);
            bl[j] = *reinterpret_cast<const bf16x8*>(&sBl[off]);
        }
        #pragma unroll
        for (int i = 0; i < 4; ++i)
            #pragma unroll
            for (int j = 0; j < 4; ++j) {
                acc[i][j] = __builtin_amdgcn_mfma_f32_16x16x32_bf16(ah[i], bh[j], acc[i][j], 0, 0, 0);
                acc[i][j] = __builtin_amdgcn_mfma_f32_16x16x32_bf16(ah[i], bl[j], acc[i][j], 0, 0, 0);
                acc[i][j] = __builtin_amdgcn_mfma_f32_16x16x32_bf16(al[i], bh[j], acc[i][j], 0, 0, 0);
            }
    }

    const int rq = (lane >> 4) * 4;
    #pragma unroll
    for (int i = 0; i < 4; ++i)
        #pragma unroll
        for (int j = 0; j < 4; ++j) {
            #pragma unroll
            for (int q = 0; q < 4; ++q) {
                C[(size_t)(bm + wr * 64 + i * 16 + rq + q) * N + bn + wc * 64 + j * 16 + fr]
                    = acc[i][j][q];
            }
        }
}

// ---------------- prep: RoPE + hi/lo split of Q,K into head-major layouts --------
// Q is pre-scaled by sm_scale = 0.125 (exact pow2). Qh/Ql: [NQH][L][64], Kh/Kl: [NKVH][L][64]
__global__ __launch_bounds__(256) void prep_qk_kernel(
    const float* __restrict__ proj,
    const float* __restrict__ cosT, const float* __restrict__ sinT,
    ushort* __restrict__ Qh, ushort* __restrict__ Ql,
    ushort* __restrict__ Kh, ushort* __restrict__ Kl)
{
    int pos = blockIdx.x;
    const float* row = proj + (size_t)pos * PROJW;
    const float* ct = cosT + pos * 32;
    const float* st = sinT + pos * 32;
    int t = threadIdx.x;
    #pragma unroll
    for (int it = 0; it < 4; ++it) {            // 1024 q pairs
        int p = t + it * 256;
        int head = p >> 5, d = p & 31;
        float x1 = row[head * HD + d], x2 = row[head * HD + d + 32];
        float c = ct[d], s = st[d];
        float y1 = (x1 * c + x2 * s) * 0.125f;
        float y2 = (-x1 * s + x2 * c) * 0.125f;
        size_t o = ((size_t)head * L_SEQ + pos) * HD + d;
        ushort h1 = f2bf(y1); Qh[o] = h1;      Ql[o] = f2bf(y1 - bf2f(h1));
        ushort h2 = f2bf(y2); Qh[o + 32] = h2; Ql[o + 32] = f2bf(y2 - bf2f(h2));
    }
    {                                            // 256 k pairs
        int head = t >> 5, d = t & 31;
        float x1 = row[DMODEL + head * HD + d], x2 = row[DMODEL + head * HD + d + 32];
        float c = ct[d], s = st[d];
        float y1 = x1 * c + x2 * s;
        float y2 = -x1 * s + x2 * c;
        size_t o = ((size_t)head * L_SEQ + pos) * HD + d;
        ushort h1 = f2bf(y1); Kh[o] = h1;      Kl[o] = f2bf(y1 - bf2f(h1));
        ushort h2 = f2bf(y2); Kh[o + 32] = h2; Kl[o + 32] = f2bf(y2 - bf2f(h2));
    }
}

// ---------------- prep: V transpose + hi/lo split. Vth/Vtl: [NKVH][64][L] --------
__global__ __launch_bounds__(256) void prep_v_kernel(const float* __restrict__ proj,
                                                     ushort* __restrict__ Vth,
                                                     ushort* __restrict__ Vtl)
{
    __shared__ float tile[64][65];
    int h = blockIdx.y, p0 = blockIdx.x * 64;
    int t = threadIdx.x;
    {   // read 64 pos x 64 d, coalesced
        int r = t >> 2, c0 = (t & 3) * 16;
        const float* src = proj + (size_t)(p0 + r) * PROJW + DMODEL + NKVH * HD + h * HD + c0;
        #pragma unroll
        for (int i = 0; i < 16; i += 4) {
            float4 v = *reinterpret_cast<const float4*>(src + i);
            tile[r][c0 + i + 0] = v.x;
            tile[r][c0 + i + 1] = v.y;
            tile[r][c0 + i + 2] = v.z;
            tile[r][c0 + i + 3] = v.w;
        }
    }
    __syncthreads();
    {   // write transposed: thread owns (d, 16-pos chunk)
        int d = t >> 2, c0 = (t & 3) * 16;
        ushort hh[16], ll[16];
        #pragma unroll
        for (int i = 0; i < 16; ++i) {
            float v = tile[c0 + i][d];
            hh[i] = f2bf(v);
            ll[i] = f2bf(v - bf2f(hh[i]));
        }
        size_t o = ((size_t)h * HD + d) * L_SEQ + p0 + c0;
        #pragma unroll
        for (int i = 0; i < 16; i += 4) {
            *reinterpret_cast<ushort4*>(&Vth[o + i]) = make_ushort4(hh[i], hh[i+1], hh[i+2], hh[i+3]);
            *reinterpret_cast<ushort4*>(&Vtl[o + i]) = make_ushort4(ll[i], ll[i+1], ll[i+2], ll[i+3]);
        }
    }
}

// ---------------- MFMA flash attention v3 (QBLK=16, 4 blocks/CU) ----------------
// 1D grid 1024: h = bid&7 (XCD affinity), q0 = (bid>>3)*16. 4 waves; wave w = head h*4+w.
// K tile (64 keys) staged in LDS (double-buffered, XOR-swizzled, global_load_lds).
// P^T round-trip per kc-phase in a 1KB/wave buffer (same-wave DS order, no barrier).
// LDS total 40KB -> 4 blocks/CU; launch_bounds(256,4) caps VGPR at 128.
// S^T = K*Q^T; O^T = V^T*P^T; online softmax seeded m=sink, l=1; inverted mask.
__global__ __launch_bounds__(256, 4) void attn_mfma_kernel(
    const ushort* __restrict__ Qh, const ushort* __restrict__ Ql,
    const ushort* __restrict__ Kh, const ushort* __restrict__ Kl,
    const ushort* __restrict__ Vth, const ushort* __restrict__ Vtl,
    const float* __restrict__ sink,
    ushort* __restrict__ out_hi, ushort* __restrict__ out_lo)
{
    __shared__ __align__(16) ushort KsH[2][4096];   // 64 rows x 128B, swizzled chunks
    __shared__ __align__(16) ushort KsL[2][4096];
    __shared__ __align__(16) ushort PtH[4][512];    // per-wave P^T phase: 16 rows x 32 keys
    __shared__ __align__(16) ushort PtL[4][512];    // row stride 64B, slot = (chunk+fr)&3

    const int tid = threadIdx.x;
    const int w = tid >> 6, lane = tid & 63;
    const int fr = lane & 15, g = lane >> 4;
    const int bid = blockIdx.x;
    const int h = bid & 7;
    const int q0 = (bid >> 3) * 16;
    const int hq = h * 4 + w;

    const ushort* Qb_h = Qh + ((size_t)hq * L_SEQ + q0) * HD;
    const ushort* Qb_l = Ql + ((size_t)hq * L_SEQ + q0) * HD;
    const ushort* Kb_h = Kh + (size_t)h * L_SEQ * HD;
    const ushort* Kb_l = Kl + (size_t)h * L_SEQ * HD;
    const ushort* Vb_h = Vth + (size_t)h * HD * L_SEQ;
    const ushort* Vb_l = Vtl + (size_t)h * HD * L_SEQ;

    // ---- skip-aware tile list (QBLK=16): skipped k0 in [kA, kB] (fully masked) ----
    // fully masked iff q0 >= k0+63 AND q0+15 < k0+SW  ->  k0 in [q0-496, q0-63]
    int sA = q0 - 496, sB = q0 - 63;
    int kA = (sA + 63) & ~63; if (kA < 0) kA = 0;
    int kB = sB & ~63;
    bool has_skip = (sB >= 0) && (kA <= kB);
    int n1 = has_skip ? (kA >> 6) : (L_SEQ >> 6);
    int kResume = has_skip ? (kB + 64) : 0;
    int nt = n1 + (has_skip ? ((L_SEQ - kResume) >> 6) : 0);
    #define K0_OF(t) ((t) < n1 ? (t) * 64 : kResume + ((t) - n1) * 64)

    // ---- stage K tile (hi+lo) into LDS buf: 4 glds per wave, source pre-swizzled ----
    #define STAGE_K(buf, k0s) do {                                                  \
        _Pragma("unroll")                                                           \
        for (int qi = 0; qi < 2; ++qi) {                                            \
            int gq = (w * 2 + qi) * 64 + lane;                                      \
            int srow = gq >> 3, sc = gq & 7;                                        \
            size_t soff = (size_t)((k0s) + srow) * HD + ((sc ^ (srow & 7)) * 8);    \
            glds16(Kb_h + soff, &KsH[buf][(w * 2 + qi) * 512]);                     \
            glds16(Kb_l + soff, &KsL[buf][(w * 2 + qi) * 512]);                     \
        }                                                                           \
    } while (0)

    // Q B-frags [kc]: col q = fr, k-dim = kc*32+g*8+e  (Q pre-scaled by 0.125)
    bf16x8 qbh[2], qbl[2];
    #pragma unroll
    for (int kc = 0; kc < 2; ++kc) {
        size_t o = (size_t)fr * HD + kc * 32 + g * 8;
        qbh[kc] = *reinterpret_cast<const bf16x8*>(Qb_h + o);
        qbl[kc] = *reinterpret_cast<const bf16x8*>(Qb_l + o);
    }

    const float sval = sink[hq];
    float m = sval;
    float l = 1.0f;
    f32x4 ot[4];
    #pragma unroll
    for (int i = 0; i < 4; ++i)
        ot[i] = (f32x4){0.0f, 0.0f, 0.0f, 0.0f};

    STAGE_K(0, K0_OF(0));
    __syncthreads();                       // drain -> K(0) resident

    for (int t = 0; t < nt; ++t) {
        const int cur = t & 1;
        if (t + 1 < nt) STAGE_K(cur ^ 1, K0_OF(t + 1));   // async prefetch next tile
        const int k0 = K0_OF(t);

        // K A-frags from LDS (swizzled read): row key = i*16+fr, chunk = kc*4+g
        bf16x8 kah[4][2], kal[4][2];
        #pragma unroll
        for (int i = 0; i < 4; ++i)
            #pragma unroll
            for (int kc = 0; kc < 2; ++kc) {
                int row = i * 16 + fr;
                int off = row * 64 + (((kc * 4 + g) ^ (row & 7)) * 8);
                kah[i][kc] = *reinterpret_cast<const bf16x8*>(&KsH[cur][off]);
                kal[i][kc] = *reinterpret_cast<const bf16x8*>(&KsL[cur][off]);
            }

        f32x4 st4[4];
        #pragma unroll
        for (int i = 0; i < 4; ++i)
            st4[i] = (f32x4){0.0f, 0.0f, 0.0f, 0.0f};
        __builtin_amdgcn_s_setprio(1);
        #pragma unroll
        for (int i = 0; i < 4; ++i)
            #pragma unroll
            for (int kc = 0; kc < 2; ++kc) {
                st4[i] = __builtin_amdgcn_mfma_f32_16x16x32_bf16(kah[i][kc], qbh[kc], st4[i], 0, 0, 0);
                st4[i] = __builtin_amdgcn_mfma_f32_16x16x32_bf16(kah[i][kc], qbl[kc], st4[i], 0, 0, 0);
                st4[i] = __builtin_amdgcn_mfma_f32_16x16x32_bf16(kal[i][kc], qbh[kc], st4[i], 0, 0, 0);
            }
        __builtin_amdgcn_s_setprio(0);

        // V A-frags direct from global (L2-resident; latency hidden under softmax)
        bf16x8 vah[4][2], val[4][2];
        #pragma unroll
        for (int i = 0; i < 4; ++i)
            #pragma unroll
            for (int kc = 0; kc < 2; ++kc) {
                size_t o = (size_t)(i * 16 + fr) * L_SEQ + k0 + kc * 32 + g * 8;
                vah[i][kc] = *reinterpret_cast<const bf16x8*>(Vb_h + o);
                val[i][kc] = *reinterpret_cast<const bf16x8*>(Vb_l + o);
            }

        // masked iff (q>=k && q<k+SW); tiles with no maskable pair skip the clamp
        const bool need_mask = (q0 + 15 >= k0) && (q0 < k0 + 63 + SW);
        const int q = q0 + fr;

        float tm = -INFINITY;
        if (need_mask) {
            #pragma unroll
            for (int i = 0; i < 4; ++i)
                #pragma unroll
                for (int r = 0; r < 4; ++r) {
                    int k = k0 + i * 16 + g * 4 + r;
                    float s = st4[i][r];
                    if ((q >= k) && (q < k + SW)) s = -INFINITY;
                    st4[i][r] = s;
                    tm = fmaxf(tm, s);
                }
        } else {
            #pragma unroll
            for (int i = 0; i < 4; ++i)
                #pragma unroll
                for (int r = 0; r < 4; ++r)
                    tm = fmaxf(tm, st4[i][r]);
        }
        tm = fmaxf(tm, __shfl_xor(tm, 16));
        tm = fmaxf(tm, __shfl_xor(tm, 32));
        float nm = fmaxf(m, tm);
        float al = __expf(m - nm);
        float ps = 0.0f;
        #pragma unroll
        for (int i = 0; i < 4; ++i)
            #pragma unroll
            for (int r = 0; r < 4; ++r) {
                float p = __expf(st4[i][r] - nm);
                st4[i][r] = p;
                ps += p;
            }
        ps += __shfl_xor(ps, 16);
        ps += __shfl_xor(ps, 32);
        l = l * al + ps;
        m = nm;
        #pragma unroll
        for (int i = 0; i < 4; ++i) ot[i] *= al;

        // ---- PV per kc phase: P^T granules -> 1KB/wave LDS -> B-frags -> 12 MFMAs ----
        // write: local key kl = iLoc*16+g*4+r; chunk cw = iLoc*2+(g>>1); half = g&1;
        //        slot = (cw+fr)&3; ushort off = fr*32 + slot*8 + half*4
        // read : chunk g (keys g*8..+7); off = fr*32 + ((g+fr)&3)*8  (same slot fn)
        #pragma unroll
        for (int kc = 0; kc < 2; ++kc) {
            #pragma unroll
            for (int iLoc = 0; iLoc < 2; ++iLoc) {
                int i = kc * 2 + iLoc;
                ushort ph[4], pl[4];
                #pragma unroll
                for (int r = 0; r < 4; ++r) {
                    float p = st4[i][r];
                    ph[r] = f2bf(p);
                    pl[r] = f2bf(p - bf2f(ph[r]));
                }
                int cw = iLoc * 2 + (g >> 1);
                int poff = fr * 32 + ((cw + fr) & 3) * 8 + (g & 1) * 4;
                *reinterpret_cast<ushort4*>(&PtH[w][poff]) = make_ushort4(ph[0], ph[1], ph[2], ph[3]);
                *reinterpret_cast<ushort4*>(&PtL[w][poff]) = make_ushort4(pl[0], pl[1], pl[2], pl[3]);
            }
            int roff = fr * 32 + (((g + fr) & 3) * 8);
            bf16x8 pbh = *reinterpret_cast<const bf16x8*>(&PtH[w][roff]);
            bf16x8 pbl = *reinterpret_cast<const bf16x8*>(&PtL[w][roff]);
            __builtin_amdgcn_s_setprio(1);
            #pragma unroll
            for (int i = 0; i < 4; ++i) {
                ot[i] = __builtin_amdgcn_mfma_f32_16x16x32_bf16(vah[i][kc], pbh, ot[i], 0, 0, 0);
                ot[i] = __builtin_amdgcn_mfma_f32_16x16x32_bf16(vah[i][kc], pbl, ot[i], 0, 0, 0);
                ot[i] = __builtin_amdgcn_mfma_f32_16x16x32_bf16(val[i][kc], pbh, ot[i], 0, 0, 0);
            }
            __builtin_amdgcn_s_setprio(0);
        }

        __syncthreads();   // K(t+1) staged; all waves done reading KsH/KsL[cur]
    }

    // epilogue: O^T frag -> out[q][hq*64+d] hi/lo; d = i*16+g*4+r, q = q0+fr
    {
        float inv = 1.0f / l;
        int q = q0 + fr;
        #pragma unroll
        for (int i = 0; i < 4; ++i) {
            ushort hh[4], ll[4];
            #pragma unroll
            for (int r = 0; r < 4; ++r) {
                float v = ot[i][r] * inv;
                hh[r] = f2bf(v);
                ll[r] = f2bf(v - bf2f(hh[r]));
            }
            size_t o = (size_t)q * DMODEL + hq * HD + i * 16 + g * 4;
            *reinterpret_cast<ushort4*>(&out_hi[o]) = make_ushort4(hh[0], hh[1], hh[2], hh[3]);
            *reinterpret_cast<ushort4*>(&out_lo[o]) = make_ushort4(ll[0], ll[1], ll[2], ll[3]);
        }
    }
    #undef STAGE_K
    #undef K0_OF
}

extern "C" void kernel_launch(void* const* d_in, const int* in_sizes, int n_in,
                              void* d_out, int out_size, void* d_ws, size_t ws_size,
                              hipStream_t stream) {
    const float* x     = (const float*)d_in[0];
    const float* W_qkv = (const float*)d_in[1];
    const float* W_out = (const float*)d_in[2];
    const float* s     = (const float*)d_in[3];
    float* outp = (float*)d_out;

    // workspace (~93 MB) with time-disjoint aliasing:
    //   xh/xl (gemm1 A)  -> reused as Qh/Ql (attn)
    //   wqh/wql (gemm1 B) -> reused as ath/atl (attn out / gemm2 A)
    char* ws = (char*)d_ws;
    float*  proj = (float*)ws;  ws += (size_t)L_SEQ * PROJW * 4;      // 25.2 MB
    float*  cosT = (float*)ws;  ws += (size_t)L_SEQ * 32 * 4;
    float*  sinT = (float*)ws;  ws += (size_t)L_SEQ * 32 * 4;
    ushort* xh   = (ushort*)ws; ws += (size_t)L_SEQ * DMODEL * 2;     // 8.39 MB (= Qh size)
    ushort* xl   = (ushort*)ws; ws += (size_t)L_SEQ * DMODEL * 2;
    ushort* wqh  = (ushort*)ws; ws += (size_t)PROJW * DMODEL * 2;     // 12.6 MB (>= ath 8.39)
    ushort* wql  = (ushort*)ws; ws += (size_t)PROJW * DMODEL * 2;
    ushort* woh  = (ushort*)ws; ws += (size_t)DMODEL * DMODEL * 2;
    ushort* wol  = (ushort*)ws; ws += (size_t)DMODEL * DMODEL * 2;
    ushort* kh   = (ushort*)ws; ws += (size_t)NKVH * L_SEQ * HD * 2;  // 2.1 MB each
    ushort* kl   = (ushort*)ws; ws += (size_t)NKVH * L_SEQ * HD * 2;
    ushort* vth  = (ushort*)ws; ws += (size_t)NKVH * HD * L_SEQ * 2;
    ushort* vtl  = (ushort*)ws; ws += (size_t)NKVH * HD * L_SEQ * 2;

    ushort* qh  = xh;    // alias: live after gemm1 is done with xh
    ushort* ql  = xl;
    ushort* ath = wqh;   // alias: live after gemm1 is done with wqh
    ushort* atl = wql;

    rope_tables_kernel<<<(L_SEQ + 255) / 256, 256, 0, stream>>>(cosT, sinT);

    split_rm_kernel<<<(L_SEQ * DMODEL) / 1024, 256, 0, stream>>>(x, xh, xl);
    split_t_kernel<<<dim3(PROJW / 32, DMODEL / 32), 256, 0, stream>>>(W_qkv, wqh, wql, DMODEL, PROJW);
    split_t_kernel<<<dim3(DMODEL / 32, DMODEL / 32), 256, 0, stream>>>(W_out, woh, wol, DMODEL, DMODEL);

    // proj = x @ W_qkv
    gemm_bf16x2_kernel<<<dim3(PROJW / 128, L_SEQ / 128), 256, 0, stream>>>(
        xh, xl, wqh, wql, proj, L_SEQ, PROJW, DMODEL);

    // RoPE + split into head-major Q/K (Q pre-scaled); transpose+split V
    prep_qk_kernel<<<L_SEQ, 256, 0, stream>>>(proj, cosT, sinT, qh, ql, kh, kl);
    prep_v_kernel<<<dim3(L_SEQ / 64, NKVH), 256, 0, stream>>>(proj, vth, vtl);

    // MFMA flash attention v3: QBLK=16, grid 1024 (4 blocks/CU), XCD-affine heads
    attn_mfma_kernel<<<(L_SEQ / 16) * NKVH, 256, 0, stream>>>(
        qh, ql, kh, kl, vth, vtl, s, ath, atl);

    // out = attn @ W_out
    gemm_bf16x2_kernel<<<dim3(DMODEL / 128, L_SEQ / 128), 256, 0, stream>>>(
        ath, atl, woh, wol, outp, L_SEQ, DMODEL, DMODEL);
}